// Round 1
// baseline (1498.208 us; speedup 1.0000x reference)
//
#include <hip/hip_runtime.h>

#define NN 50000
#define NE 800000

// ---- degrees ---------------------------------------------------------------
__global__ void degree_kernel(const int* __restrict__ src, const int* __restrict__ dst,
                              float* __restrict__ dout, float* __restrict__ din) {
    int e = blockIdx.x * 256 + threadIdx.x;
    if (e < NE) {
        atomicAdd(&dout[src[e]], 1.0f);
        atomicAdd(&din[dst[e]], 1.0f);
    }
}

__global__ void rsqrt_kernel(float* __restrict__ d, int n) {
    int i = blockIdx.x * 256 + threadIdx.x;
    if (i < n) d[i] = rsqrtf(fmaxf(d[i], 1.0f));
}

// ---- X = rowscale(A) @ W  (W is K x 64, staged in LDS) ---------------------
// scale==nullptr -> no row scaling. Each block: 4 rows, 64 cols/row.
template <int K>
__global__ __launch_bounds__(256) void proj_kernel(
    const float* __restrict__ A, int lda,
    const float* __restrict__ W,
    const float* __restrict__ scale,
    float* __restrict__ X) {
    __shared__ float sW[K * 64];
    for (int i = threadIdx.x; i < K * 64; i += 256) sW[i] = W[i];
    __syncthreads();
    int r = blockIdx.x * 4 + (threadIdx.x >> 6);
    int c = threadIdx.x & 63;
    if (r >= NN) return;
    const float* a = A + (size_t)r * lda;
    float acc = 0.0f;
#pragma unroll
    for (int k = 0; k < K; k += 4) {
        float4 a4 = *reinterpret_cast<const float4*>(a + k);
        acc = fmaf(a4.x, sW[(k + 0) * 64 + c], acc);
        acc = fmaf(a4.y, sW[(k + 1) * 64 + c], acc);
        acc = fmaf(a4.z, sW[(k + 2) * 64 + c], acc);
        acc = fmaf(a4.w, sW[(k + 3) * 64 + c], acc);
    }
    if (scale) acc *= scale[r];
    X[(size_t)r * 64 + c] = acc;
}

// ---- push scatter: C[dst, coff:coff+64] += X[src, 0:64] --------------------
__global__ __launch_bounds__(256) void scatter_kernel(
    const int* __restrict__ src, const int* __restrict__ dst,
    const float* __restrict__ X, float* __restrict__ C,
    int ldc, int coff) {
    unsigned t = blockIdx.x * 256u + threadIdx.x;
    unsigned e = t >> 6;
    int c = t & 63;
    if (e >= NE) return;
    int s = src[e], d = dst[e];
    float v = X[(size_t)s * 64 + c];
    atomicAdd(&C[(size_t)d * ldc + coff + c], v);
}

// ---- epilogue: C[n, coff+c] = relu(C * din_is[n] + b[c]) -------------------
__global__ void relu_norm_kernel(float* __restrict__ C, const float* __restrict__ din_is,
                                 const float* __restrict__ b, int coff) {
    unsigned t = blockIdx.x * 256u + threadIdx.x;
    unsigned n = t >> 6;
    int c = t & 63;
    if (n >= NN) return;
    float* p = C + (size_t)n * 256 + coff + c;
    *p = fmaxf(fmaf(*p, din_is[n], b[c]), 0.0f);
}

// ---- out init with bias ----------------------------------------------------
__global__ void init_out_kernel(float* __restrict__ out, const float* __restrict__ b) {
    unsigned t = blockIdx.x * 256u + threadIdx.x;
    if (t < (unsigned)NN * 64u) out[t] = b[t & 63];
}

extern "C" void kernel_launch(void* const* d_in, const int* in_sizes, int n_in,
                              void* d_out, int out_size, void* d_ws, size_t ws_size,
                              hipStream_t stream) {
    const float* feat  = (const float*)d_in[0];
    const int*   src   = (const int*)d_in[1];
    const int*   dst   = (const int*)d_in[2];
    const float* W[4]  = {(const float*)d_in[3], (const float*)d_in[5],
                          (const float*)d_in[7], (const float*)d_in[9]};
    const float* b[4]  = {(const float*)d_in[4], (const float*)d_in[6],
                          (const float*)d_in[8], (const float*)d_in[10]};
    const float* W_mlp = (const float*)d_in[11];
    const float* b_mlp = (const float*)d_in[12];
    float* out = (float*)d_out;

    // workspace layout (floats): C [NN*256] | X [NN*64] | dout_is [NN] | din_is [NN]
    float* C       = (float*)d_ws;
    float* X       = C + (size_t)NN * 256;
    float* dout_is = X + (size_t)NN * 64;
    float* din_is  = dout_is + NN;

    hipMemsetAsync(dout_is, 0, 2 * NN * sizeof(float), stream);
    hipMemsetAsync(C, 0, (size_t)NN * 256 * sizeof(float), stream);

    degree_kernel<<<(NE + 255) / 256, 256, 0, stream>>>(src, dst, dout_is, din_is);
    rsqrt_kernel<<<(2 * NN + 255) / 256, 256, 0, stream>>>(dout_is, 2 * NN);

    // layer 0 (K = 256 input feats)
    proj_kernel<256><<<12500, 256, 0, stream>>>(feat, 256, W[0], dout_is, X);
    scatter_kernel<<<(NE * 64) / 256, 256, 0, stream>>>(src, dst, X, C, 256, 0);
    relu_norm_kernel<<<(NN * 64) / 256, 256, 0, stream>>>(C, din_is, b[0], 0);

    // layers 1..3 (K = 64), input = previous slice of C
    for (int i = 1; i < 4; ++i) {
        proj_kernel<64><<<12500, 256, 0, stream>>>(C + (i - 1) * 64, 256, W[i], dout_is, X);
        scatter_kernel<<<(NE * 64) / 256, 256, 0, stream>>>(src, dst, X, C, 256, i * 64);
        relu_norm_kernel<<<(NN * 64) / 256, 256, 0, stream>>>(C, din_is, b[i], i * 64);
    }

    // tail: P = C @ W_mlp (project BEFORE the neighbor-sum; matmul is linear),
    // then out = b_mlp + segment_sum(P[src] -> dst)
    proj_kernel<256><<<12500, 256, 0, stream>>>(C, 256, W_mlp, nullptr, X);
    init_out_kernel<<<(NN * 64) / 256, 256, 0, stream>>>(out, b_mlp);
    scatter_kernel<<<(NE * 64) / 256, 256, 0, stream>>>(src, dst, X, out, 64, 0);
}

// Round 2
// 818.543 us; speedup vs baseline: 1.8303x; 1.8303x over previous
//
#include <hip/hip_runtime.h>

#define NN 50000
#define NE 800000

// ---- degrees (float counts; exact for counts << 2^24) ----------------------
__global__ void degree_kernel(const int* __restrict__ src, const int* __restrict__ dst,
                              float* __restrict__ dout, float* __restrict__ din) {
    int e = blockIdx.x * 256 + threadIdx.x;
    if (e < NE) {
        atomicAdd(&dout[src[e]], 1.0f);
        atomicAdd(&din[dst[e]], 1.0f);
    }
}

__global__ void rsqrt_kernel(float* __restrict__ d, int n) {
    int i = blockIdx.x * 256 + threadIdx.x;
    if (i < n) d[i] = rsqrtf(fmaxf(d[i], 1.0f));
}

// ---- scan helpers ----------------------------------------------------------
__device__ inline int wave_incl_scan(int v) {
    int lane = threadIdx.x & 63;
#pragma unroll
    for (int off = 1; off < 64; off <<= 1) {
        int t = __shfl_up(v, off, 64);
        if (lane >= off) v += t;
    }
    return v;
}

// A: per-block local exclusive scan of in-degree; block totals to partials
__global__ void scan_local_kernel(const float* __restrict__ din,
                                  int* __restrict__ row_start,
                                  int* __restrict__ partials) {
    __shared__ int wsum[4];
    int i = blockIdx.x * 256 + threadIdx.x;
    int v = (i < NN) ? (int)din[i] : 0;
    int lane = threadIdx.x & 63, wid = threadIdx.x >> 6;
    int incl = wave_incl_scan(v);
    if (lane == 63) wsum[wid] = incl;
    __syncthreads();
    if (threadIdx.x == 0) {
        int s = 0;
        for (int w = 0; w < 4; ++w) { int t = wsum[w]; wsum[w] = s; s += t; }
        partials[blockIdx.x] = s;
    }
    __syncthreads();
    if (i < NN) row_start[i] = incl - v + wsum[wid];
}

// B: single-block exclusive scan of the 196 partials (in place)
__global__ void scan_partials_kernel(int* __restrict__ partials, int nparts,
                                     int* __restrict__ row_start) {
    __shared__ int wsum[4];
    int v = (threadIdx.x < nparts) ? partials[threadIdx.x] : 0;
    int lane = threadIdx.x & 63, wid = threadIdx.x >> 6;
    int incl = wave_incl_scan(v);
    if (lane == 63) wsum[wid] = incl;
    __syncthreads();
    if (threadIdx.x == 0) {
        int s = 0;
        for (int w = 0; w < 4; ++w) { int t = wsum[w]; wsum[w] = s; s += t; }
        row_start[NN] = NE;  // total in-degree == edge count
    }
    __syncthreads();
    if (threadIdx.x < nparts) partials[threadIdx.x] = incl - v + wsum[wid];
}

// C: add block offsets
__global__ void scan_add_kernel(int* __restrict__ row_start, const int* __restrict__ partials) {
    int i = blockIdx.x * 256 + threadIdx.x;
    if (i < NN) row_start[i] += partials[blockIdx.x];
}

// fill CSR: group src by dst
__global__ void csr_fill_kernel(const int* __restrict__ src, const int* __restrict__ dst,
                                const int* __restrict__ row_start, int* __restrict__ cursor,
                                int* __restrict__ csr_src) {
    int e = blockIdx.x * 256 + threadIdx.x;
    if (e < NE) {
        int d = dst[e];
        int pos = atomicAdd(&cursor[d], 1);
        csr_src[row_start[d] + pos] = src[e];
    }
}

// ---- X = rowscale(A) @ W  (W is K x 64, staged in LDS) ---------------------
template <int K>
__global__ __launch_bounds__(256) void proj_kernel(
    const float* __restrict__ A, int lda,
    const float* __restrict__ W,
    const float* __restrict__ scale,
    float* __restrict__ X) {
    __shared__ float sW[K * 64];
    for (int i = threadIdx.x; i < K * 64; i += 256) sW[i] = W[i];
    __syncthreads();
    int r = blockIdx.x * 4 + (threadIdx.x >> 6);
    int c = threadIdx.x & 63;
    if (r >= NN) return;
    const float* a = A + (size_t)r * lda;
    float acc = 0.0f;
#pragma unroll
    for (int k = 0; k < K; k += 4) {
        float4 a4 = *reinterpret_cast<const float4*>(a + k);
        acc = fmaf(a4.x, sW[(k + 0) * 64 + c], acc);
        acc = fmaf(a4.y, sW[(k + 1) * 64 + c], acc);
        acc = fmaf(a4.z, sW[(k + 2) * 64 + c], acc);
        acc = fmaf(a4.w, sW[(k + 3) * 64 + c], acc);
    }
    if (scale) acc *= scale[r];
    X[(size_t)r * 64 + c] = acc;
}

// ---- pull-mode aggregation: one wave per dst node, lane = column -----------
// din_is != nullptr: out[n, coff+c] = relu(sum * din_is[n] + b[c])   (layer)
// din_is == nullptr: out[n, coff+c] = sum + b[c]                     (tail)
__global__ __launch_bounds__(256) void gather_kernel(
    const int* __restrict__ row_start, const int* __restrict__ csr_src,
    const float* __restrict__ X, const float* __restrict__ din_is,
    const float* __restrict__ b, float* __restrict__ out,
    int ldo, int coff) {
    int n = blockIdx.x * 4 + (threadIdx.x >> 6);
    int c = threadIdx.x & 63;
    if (n >= NN) return;
    int s0 = row_start[n], s1 = row_start[n + 1];
    float acc0 = 0.0f, acc1 = 0.0f;
    int i = s0;
    int n4 = s0 + ((s1 - s0) & ~3);
    for (; i < n4; i += 4) {
        int sa = csr_src[i], sb = csr_src[i + 1], sc = csr_src[i + 2], sd = csr_src[i + 3];
        acc0 += X[(size_t)sa * 64 + c];
        acc1 += X[(size_t)sb * 64 + c];
        acc0 += X[(size_t)sc * 64 + c];
        acc1 += X[(size_t)sd * 64 + c];
    }
    for (; i < s1; ++i) acc0 += X[(size_t)csr_src[i] * 64 + c];
    float acc = acc0 + acc1;
    float* p = out + (size_t)n * ldo + coff + c;
    if (din_is) {
        *p = fmaxf(fmaf(acc, din_is[n], b[c]), 0.0f);
    } else {
        *p = acc + b[c];
    }
}

extern "C" void kernel_launch(void* const* d_in, const int* in_sizes, int n_in,
                              void* d_out, int out_size, void* d_ws, size_t ws_size,
                              hipStream_t stream) {
    const float* feat  = (const float*)d_in[0];
    const int*   src   = (const int*)d_in[1];
    const int*   dst   = (const int*)d_in[2];
    const float* W[4]  = {(const float*)d_in[3], (const float*)d_in[5],
                          (const float*)d_in[7], (const float*)d_in[9]};
    const float* b[4]  = {(const float*)d_in[4], (const float*)d_in[6],
                          (const float*)d_in[8], (const float*)d_in[10]};
    const float* W_mlp = (const float*)d_in[11];
    const float* b_mlp = (const float*)d_in[12];
    float* out = (float*)d_out;

    // workspace layout:
    // C [NN*256 f] | X [NN*64 f] | dout_is [NN f] | din_is [NN f] |
    // cursor [NN i] | row_start [NN+1 i] | partials [256 i] | csr_src [NE i]
    float* C       = (float*)d_ws;
    float* X       = C + (size_t)NN * 256;
    float* dout_is = X + (size_t)NN * 64;
    float* din_is  = dout_is + NN;
    int*   cursor    = (int*)(din_is + NN);
    int*   row_start = cursor + NN;
    int*   partials  = row_start + NN + 1;
    int*   csr_src   = partials + 256;

    const int NBLK = (NN + 255) / 256;  // 196

    // zero: dout_is, din_is, cursor (contiguous)
    hipMemsetAsync(dout_is, 0, 3 * NN * sizeof(float), stream);

    degree_kernel<<<(NE + 255) / 256, 256, 0, stream>>>(src, dst, dout_is, din_is);

    // CSR build (uses integer view of din before rsqrt)
    scan_local_kernel<<<NBLK, 256, 0, stream>>>(din_is, row_start, partials);
    scan_partials_kernel<<<1, 256, 0, stream>>>(partials, NBLK, row_start);
    scan_add_kernel<<<NBLK, 256, 0, stream>>>(row_start, partials);
    csr_fill_kernel<<<(NE + 255) / 256, 256, 0, stream>>>(src, dst, row_start, cursor, csr_src);

    rsqrt_kernel<<<(2 * NN + 255) / 256, 256, 0, stream>>>(dout_is, 2 * NN);

    // layer 0 (K = 256 input feats)
    proj_kernel<256><<<12500, 256, 0, stream>>>(feat, 256, W[0], dout_is, X);
    gather_kernel<<<12500, 256, 0, stream>>>(row_start, csr_src, X, din_is, b[0], C, 256, 0);

    // layers 1..3 (K = 64), input = previous slice of C
    for (int i = 1; i < 4; ++i) {
        proj_kernel<64><<<12500, 256, 0, stream>>>(C + (i - 1) * 64, 256, W[i], dout_is, X);
        gather_kernel<<<12500, 256, 0, stream>>>(row_start, csr_src, X, din_is, b[i], C, 256, i * 64);
    }

    // tail: P = C @ W_mlp (project BEFORE the neighbor-sum; matmul is linear),
    // then out = b_mlp + segment_sum(P[src] -> dst)
    proj_kernel<256><<<12500, 256, 0, stream>>>(C, 256, W_mlp, nullptr, X);
    gather_kernel<<<12500, 256, 0, stream>>>(row_start, csr_src, X, nullptr, b_mlp, out, 64, 0);
}

// Round 4
// 508.574 us; speedup vs baseline: 2.9459x; 1.6095x over previous
//
#include <hip/hip_runtime.h>

#define NN 50000
#define NE 800000

// ---- degrees: exact int atomics --------------------------------------------
__global__ void degree_kernel(const int* __restrict__ src, const int* __restrict__ dst,
                              int* __restrict__ dout_cnt, int* __restrict__ din_cnt) {
    int e = blockIdx.x * 256 + threadIdx.x;
    if (e < NE) {
        atomicAdd(&dout_cnt[src[e]], 1);
        atomicAdd(&din_cnt[dst[e]], 1);
    }
}

// counts (2*NN ints, contiguous dout_cnt|din_cnt) -> rsqrt floats (separate bufs)
__global__ void make_rsqrt_kernel(const int* __restrict__ cnt, float* __restrict__ is) {
    int i = blockIdx.x * 256 + threadIdx.x;
    if (i < 2 * NN) is[i] = rsqrtf(fmaxf((float)cnt[i], 1.0f));
}

// ---- scan helpers ----------------------------------------------------------
__device__ inline int wave_incl_scan(int v) {
    int lane = threadIdx.x & 63;
#pragma unroll
    for (int off = 1; off < 64; off <<= 1) {
        int t = __shfl_up(v, off, 64);
        if (lane >= off) v += t;
    }
    return v;
}

// A: per-block local exclusive scan of in-degree; block totals to partials
__global__ void scan_local_kernel(const int* __restrict__ din_cnt,
                                  int* __restrict__ row_start,
                                  int* __restrict__ partials) {
    __shared__ int wsum[4];
    int i = blockIdx.x * 256 + threadIdx.x;
    int v = (i < NN) ? din_cnt[i] : 0;
    int lane = threadIdx.x & 63, wid = threadIdx.x >> 6;
    int incl = wave_incl_scan(v);
    if (lane == 63) wsum[wid] = incl;
    __syncthreads();
    if (threadIdx.x == 0) {
        int s = 0;
        for (int w = 0; w < 4; ++w) { int t = wsum[w]; wsum[w] = s; s += t; }
        partials[blockIdx.x] = s;
    }
    __syncthreads();
    if (i < NN) row_start[i] = incl - v + wsum[wid];
}

// B: single-block exclusive scan of the 196 partials (in place)
__global__ void scan_partials_kernel(int* __restrict__ partials, int nparts,
                                     int* __restrict__ row_start) {
    __shared__ int wsum[4];
    int v = (threadIdx.x < nparts) ? partials[threadIdx.x] : 0;
    int lane = threadIdx.x & 63, wid = threadIdx.x >> 6;
    int incl = wave_incl_scan(v);
    if (lane == 63) wsum[wid] = incl;
    __syncthreads();
    if (threadIdx.x == 0) {
        int s = 0;
        for (int w = 0; w < 4; ++w) { int t = wsum[w]; wsum[w] = s; s += t; }
        row_start[NN] = NE;  // total in-degree == edge count
    }
    __syncthreads();
    if (threadIdx.x < nparts) partials[threadIdx.x] = incl - v + wsum[wid];
}

// C: add block offsets
__global__ void scan_add_kernel(int* __restrict__ row_start, const int* __restrict__ partials) {
    int i = blockIdx.x * 256 + threadIdx.x;
    if (i < NN) row_start[i] += partials[blockIdx.x];
}

// fill CSR: group src by dst
__global__ void csr_fill_kernel(const int* __restrict__ src, const int* __restrict__ dst,
                                const int* __restrict__ row_start, int* __restrict__ cursor,
                                int* __restrict__ csr_src) {
    int e = blockIdx.x * 256 + threadIdx.x;
    if (e < NE) {
        int d = dst[e];
        int pos = atomicAdd(&cursor[d], 1);
        csr_src[row_start[d] + pos] = src[e];
    }
}

// ---- X = rowscale(A) @ W, register-blocked 64x64 tile ----------------------
// Block: 256 threads -> 64 rows x 64 cols, 4x4 acc per thread.
// A staged TRANSPOSED in LDS (pitch 68); W staged row-major. Staged row index
// is CLAMPED to NN-1 (always-in-bounds loads, no predicated load); stores are
// guarded, so tail-tile duplicates are computed but never written.
template <int K>
__global__ __launch_bounds__(256) void proj_kernel(
    const float* __restrict__ A, int lda,
    const float* __restrict__ W,   // K x 64, row-major
    const float* __restrict__ scale,
    float* __restrict__ X) {
    constexpr int KC = 64;
    constexpr int NCHUNK = K / KC;
    __shared__ float sAT[KC * 68];  // [k][row], pitch 68
    __shared__ float sW[KC * 64];   // [k][col]
    float acc[4][4] = {};

    const int t = threadIdx.x;
    const int tx = t & 15;          // col group: cols 4*tx..4*tx+3
    const int ty = t >> 4;          // row group: rows 4*ty..4*ty+3
    const int row0 = blockIdx.x * 64;

    const int srow = t & 63;        // staging: one row per lane
    const int f0 = t >> 6;          // staging float4-col base (0..3)
    int grow = row0 + srow;
    if (grow > NN - 1) grow = NN - 1;   // clamp: loads always in-bounds
    const float* arow = A + (size_t)grow * lda;

    for (int kc = 0; kc < NCHUNK; ++kc) {
        // stage A chunk transposed: sAT[k][srow] = A[grow][kc*64 + k]
#pragma unroll
        for (int it = 0; it < 4; ++it) {
            int k = (f0 + it * 4) * 4;
            float4 a4 = *reinterpret_cast<const float4*>(arow + kc * KC + k);
            sAT[(k + 0) * 68 + srow] = a4.x;
            sAT[(k + 1) * 68 + srow] = a4.y;
            sAT[(k + 2) * 68 + srow] = a4.z;
            sAT[(k + 3) * 68 + srow] = a4.w;
        }
        // stage W chunk coalesced (64x64 floats = 1024 float4)
        {
            const float4* wsrc = reinterpret_cast<const float4*>(W + (size_t)kc * KC * 64);
            float4* wdst = reinterpret_cast<float4*>(sW);
#pragma unroll
            for (int it = 0; it < 4; ++it) wdst[t + it * 256] = wsrc[t + it * 256];
        }
        __syncthreads();
#pragma unroll 8
        for (int k = 0; k < KC; ++k) {
            float4 av = *reinterpret_cast<const float4*>(&sAT[k * 68 + ty * 4]);
            float4 wv = *reinterpret_cast<const float4*>(&sW[k * 64 + tx * 4]);
            acc[0][0] = fmaf(av.x, wv.x, acc[0][0]);
            acc[0][1] = fmaf(av.x, wv.y, acc[0][1]);
            acc[0][2] = fmaf(av.x, wv.z, acc[0][2]);
            acc[0][3] = fmaf(av.x, wv.w, acc[0][3]);
            acc[1][0] = fmaf(av.y, wv.x, acc[1][0]);
            acc[1][1] = fmaf(av.y, wv.y, acc[1][1]);
            acc[1][2] = fmaf(av.y, wv.z, acc[1][2]);
            acc[1][3] = fmaf(av.y, wv.w, acc[1][3]);
            acc[2][0] = fmaf(av.z, wv.x, acc[2][0]);
            acc[2][1] = fmaf(av.z, wv.y, acc[2][1]);
            acc[2][2] = fmaf(av.z, wv.z, acc[2][2]);
            acc[2][3] = fmaf(av.z, wv.w, acc[2][3]);
            acc[3][0] = fmaf(av.w, wv.x, acc[3][0]);
            acc[3][1] = fmaf(av.w, wv.y, acc[3][1]);
            acc[3][2] = fmaf(av.w, wv.z, acc[3][2]);
            acc[3][3] = fmaf(av.w, wv.w, acc[3][3]);
        }
        __syncthreads();
    }
    // store: X[r, 4tx..4tx+3], row-scale applied here
#pragma unroll
    for (int i = 0; i < 4; ++i) {
        int r = row0 + ty * 4 + i;
        if (r < NN) {
            float s = scale ? scale[r] : 1.0f;
            float4 o = {acc[i][0] * s, acc[i][1] * s, acc[i][2] * s, acc[i][3] * s};
            *reinterpret_cast<float4*>(X + (size_t)r * 64 + tx * 4) = o;
        }
    }
}

// ---- pull-mode aggregation: one wave per dst node, lane = column -----------
// din_is != nullptr: out[n, coff+c] = relu(sum * din_is[n] + b[c])   (layer)
// din_is == nullptr: out[n, coff+c] = sum + b[c]                     (tail)
__global__ __launch_bounds__(256) void gather_kernel(
    const int* __restrict__ row_start, const int* __restrict__ csr_src,
    const float* __restrict__ X, const float* __restrict__ din_is,
    const float* __restrict__ b, float* __restrict__ out,
    int ldo, int coff) {
    int n = blockIdx.x * 4 + (threadIdx.x >> 6);
    int c = threadIdx.x & 63;
    if (n >= NN) return;
    int s0 = row_start[n], s1 = row_start[n + 1];
    float acc0 = 0.0f, acc1 = 0.0f;
    int i = s0;
    int n4 = s0 + ((s1 - s0) & ~3);
    for (; i < n4; i += 4) {
        int sa = csr_src[i], sb = csr_src[i + 1], sc = csr_src[i + 2], sd = csr_src[i + 3];
        acc0 += X[(size_t)sa * 64 + c];
        acc1 += X[(size_t)sb * 64 + c];
        acc0 += X[(size_t)sc * 64 + c];
        acc1 += X[(size_t)sd * 64 + c];
    }
    for (; i < s1; ++i) acc0 += X[(size_t)csr_src[i] * 64 + c];
    float acc = acc0 + acc1;
    float* p = out + (size_t)n * ldo + coff + c;
    if (din_is) {
        *p = fmaxf(fmaf(acc, din_is[n], b[c]), 0.0f);
    } else {
        *p = acc + b[c];
    }
}

extern "C" void kernel_launch(void* const* d_in, const int* in_sizes, int n_in,
                              void* d_out, int out_size, void* d_ws, size_t ws_size,
                              hipStream_t stream) {
    const float* feat  = (const float*)d_in[0];
    const int*   src   = (const int*)d_in[1];
    const int*   dst   = (const int*)d_in[2];
    const float* W[4]  = {(const float*)d_in[3], (const float*)d_in[5],
                          (const float*)d_in[7], (const float*)d_in[9]};
    const float* b[4]  = {(const float*)d_in[4], (const float*)d_in[6],
                          (const float*)d_in[8], (const float*)d_in[10]};
    const float* W_mlp = (const float*)d_in[11];
    const float* b_mlp = (const float*)d_in[12];
    float* out = (float*)d_out;

    // workspace layout:
    // C [NN*256 f] | X [NN*64 f] | dout_is [NN f] | din_is [NN f] |
    // dout_cnt [NN i] | din_cnt [NN i] | cursor [NN i] |
    // row_start [NN+1 i] | partials [256 i] | csr_src [NE i]
    float* C       = (float*)d_ws;
    float* X       = C + (size_t)NN * 256;
    float* dout_is = X + (size_t)NN * 64;
    float* din_is  = dout_is + NN;
    int*   dout_cnt  = (int*)(din_is + NN);
    int*   din_cnt   = dout_cnt + NN;
    int*   cursor    = din_cnt + NN;
    int*   row_start = cursor + NN;
    int*   partials  = row_start + NN + 1;
    int*   csr_src   = partials + 256;

    const int NBLK = (NN + 255) / 256;   // 196
    const int GBLK = (NN + 63) / 64;     // 782 (GEMM tiles)

    // zero: dout_cnt, din_cnt, cursor (contiguous ints)
    hipMemsetAsync(dout_cnt, 0, 3 * NN * sizeof(int), stream);

    degree_kernel<<<(NE + 255) / 256, 256, 0, stream>>>(src, dst, dout_cnt, din_cnt);

    // CSR build (int in-degrees)
    scan_local_kernel<<<NBLK, 256, 0, stream>>>(din_cnt, row_start, partials);
    scan_partials_kernel<<<1, 256, 0, stream>>>(partials, NBLK, row_start);
    scan_add_kernel<<<NBLK, 256, 0, stream>>>(row_start, partials);
    csr_fill_kernel<<<(NE + 255) / 256, 256, 0, stream>>>(src, dst, row_start, cursor, csr_src);

    // counts -> rsqrt normalizers (separate output buffers, no aliasing)
    make_rsqrt_kernel<<<(2 * NN + 255) / 256, 256, 0, stream>>>(dout_cnt, dout_is);

    // layer 0 (K = 256 input feats)
    proj_kernel<256><<<GBLK, 256, 0, stream>>>(feat, 256, W[0], dout_is, X);
    gather_kernel<<<12500, 256, 0, stream>>>(row_start, csr_src, X, din_is, b[0], C, 256, 0);

    // layers 1..3 (K = 64), input = previous slice of C
    for (int i = 1; i < 4; ++i) {
        proj_kernel<64><<<GBLK, 256, 0, stream>>>(C + (i - 1) * 64, 256, W[i], dout_is, X);
        gather_kernel<<<12500, 256, 0, stream>>>(row_start, csr_src, X, din_is, b[i], C, 256, i * 64);
    }

    // tail: P = C @ W_mlp (project BEFORE the neighbor-sum; matmul is linear),
    // then out = b_mlp + segment_sum(P[src] -> dst)
    proj_kernel<256><<<GBLK, 256, 0, stream>>>(C, 256, W_mlp, nullptr, X);
    gather_kernel<<<12500, 256, 0, stream>>>(row_start, csr_src, X, nullptr, b_mlp, out, 64, 0);
}